// Round 1
// baseline (501.963 us; speedup 1.0000x reference)
//
#include <hip/hip_runtime.h>
#include <math.h>

#define N 6144
#define H 4
#define D 64          // vector dim (DOUT-1)
#define CAP 128       // max neighbors per row (binomial mean 32, 128 is ~17 sigma)
#define MINF 1e-15f
#define ONE_EPS  1.0000001192092896f   // fp32(1.0 + 1e-7)
#define ONE_MEPS 0.9999998807907104f   // fp32(1.0 - 1e-7)

__device__ __forceinline__ float wave_reduce_sum(float v) {
    v += __shfl_xor(v, 32, 64);
    v += __shfl_xor(v, 16, 64);
    v += __shfl_xor(v, 8, 64);
    v += __shfl_xor(v, 4, 64);
    v += __shfl_xor(v, 2, 64);
    v += __shfl_xor(v, 1, 64);
    return v;
}

__device__ __forceinline__ float arcosh_f(float z) {
    return logf(z + sqrtf(fmaxf(z * z - 1.0f, 0.0f)));
}

// ---------------- K1: build CSR of adj^T ----------------
// adj row-major (N,N). adj_t[i][j] = adj[j][i]. For each nonzero adj[j][i],
// append j to row i's neighbor list.
__global__ void k_build_csr(const float* __restrict__ adj,
                            int* __restrict__ cnt, int* __restrict__ idx) {
    const unsigned total4 = (unsigned)N * N / 4;
    const float4* a4 = (const float4*)adj;
    for (unsigned e = blockIdx.x * blockDim.x + threadIdx.x; e < total4;
         e += gridDim.x * blockDim.x) {
        float4 v = a4[e];
        unsigned base = e * 4u;
        float vals[4] = {v.x, v.y, v.z, v.w};
        #pragma unroll
        for (int q = 0; q < 4; q++) {
            if (vals[q] > 0.01f) {
                unsigned t = base + q;
                int j = t / N;
                int i = t % N;
                int pos = atomicAdd(&cnt[i], 1);
                if (pos < CAP) idx[i * CAP + pos] = j;
            }
        }
    }
}

// ---------------- K2: logmap0 of x (vector part only) ----------------
__global__ void k_logmap_x(const float* __restrict__ x, float* __restrict__ lmv) {
    int i = blockIdx.x * 4 + (threadIdx.x >> 6);
    int lane = threadIdx.x & 63;
    float y = x[i * 65 + 1 + lane];
    float ss = wave_reduce_sum(y * y);
    float n = fmaxf(sqrtf(ss), MINF);
    float t = fmaxf(x[i * 65], ONE_EPS);
    lmv[i * 64 + lane] = arcosh_f(t) * y / n;
}

// ---------------- K3: per-head linears: att = hyp_linear(x,Wa), red->pv,lam --------
__global__ void k_head_linear(const float* __restrict__ lmv,
                              const float* __restrict__ W_att,
                              const float* __restrict__ W_data,
                              float* __restrict__ att0, float* __restrict__ attv,
                              float* __restrict__ pv, float* __restrict__ lam) {
    __shared__ float WaT[64 * 64];
    __shared__ float WdT[64 * 64];
    int h = blockIdx.y;
    const float* Wa = W_att + h * 65 * 65;
    const float* Wd = W_data + h * 65 * 65;
    for (int t = threadIdx.x; t < 4096; t += 256) {
        int k = t & 63, d = t >> 6;
        WaT[k * 64 + d] = Wa[(1 + d) * 65 + 1 + k];
        WdT[k * 64 + d] = Wd[(1 + d) * 65 + 1 + k];
    }
    __syncthreads();
    int wave = threadIdx.x >> 6, lane = threadIdx.x & 63;
    for (int nb = wave; nb < 64; nb += 4) {
        int i = blockIdx.x * 64 + nb;
        float lmreg = lmv[i * 64 + lane];
        float ua = 0.f, ud = 0.f;
        #pragma unroll 8
        for (int k = 0; k < 64; k++) {
            float l = __shfl(lmreg, k, 64);
            ua += l * WaT[k * 64 + lane];
            ud += l * WdT[k * 64 + lane];
        }
        // att = hyp_proj(expmap0([_, ua])):
        float na = fmaxf(sqrtf(wave_reduce_sum(ua * ua)), MINF);
        float sha = sinhf(na);
        float av = sha * ua / na;
        attv[((size_t)h * N + i) * 64 + lane] = av;
        if (lane == 0) att0[h * N + i] = coshf(na);
        // red -> pv, lam
        float nd = fmaxf(sqrtf(wave_reduce_sum(ud * ud)), MINF);
        float shd = sinhf(nd), chd = coshf(nd);
        float pvd = (shd * ud / nd) / (chd + 1.0f);
        pv[((size_t)h * N + i) * 64 + lane] = pvd;
        float sp = wave_reduce_sum(pvd * pvd);
        if (lane == 0) lam[h * N + i] = 2.0f / fmaxf(1.0f - sp, MINF);
    }
}

// ---------------- K4: sparse attention + Mobius aggregation ----------------
__global__ void k_attn_agg(const int* __restrict__ cnt, const int* __restrict__ idx,
                           const float* __restrict__ att0, const float* __restrict__ attv,
                           const float* __restrict__ pv, const float* __restrict__ lam,
                           float* __restrict__ lm2) {
    int h = blockIdx.y;
    int i = blockIdx.x * 4 + (threadIdx.x >> 6);
    int lane = threadIdx.x & 63;
    const float* attvh = attv + (size_t)h * N * 64;
    const float* pvh = pv + (size_t)h * N * 64;
    float ai0 = att0[h * N + i];
    float aiv = attvh[(size_t)i * 64 + lane];
    float accn = 0.f, accd = 0.f, accss = 0.f;
    int nn = min(cnt[i], CAP);
    for (int t = 0; t < nn; t++) {
        int j = idx[i * CAP + t];
        float ajv = attvh[(size_t)j * 64 + lane];
        float dot = wave_reduce_sum(aiv * ajv);
        float theta = fmaxf(ai0 * att0[h * N + j] - dot, ONE_EPS);
        float ar = arcosh_f(theta);
        float S = fminf(ar * ar, 50.0f);
        float lj = lam[h * N + j];
        accn -= S * lj * pvh[(size_t)j * 64 + lane];
        accd += S * (lj - 1.0f);
        accss += S * S;
    }
    float norm = fmaxf(sqrtf(accss), 1e-12f);
    float den = fmaxf(accd / norm, MINF);
    float v = (accn / norm) / den;
    // mobius_half
    float nv = fmaxf(sqrtf(wave_reduce_sum(v * v)), MINF);
    float nc = fminf(nv, ONE_MEPS);
    float mh = tanhf(0.5f * atanhf(nc));
    float md = mh * v / nv;
    // to_hyperboloid
    float s = wave_reduce_sum(md * md);
    float Dh = fmaxf(1.0f - s, MINF);
    float hb0 = (1.0f + s) / Dh;
    float hbv = 2.0f * md / Dh;
    // logmap0 (vector part)
    float nh = fmaxf(sqrtf(wave_reduce_sum(hbv * hbv)), MINF);
    float t2 = fmaxf(hb0, ONE_EPS);
    lm2[((size_t)h * N + i) * 64 + lane] = arcosh_f(t2) * hbv / nh;
}

// ---------------- K5: per-head output linear -> poincare coords into p -------
__global__ void k_out_linear(const float* __restrict__ lm2,
                             const float* __restrict__ W_out,
                             float* __restrict__ p) {
    __shared__ float WoT[64 * 64];
    int h = blockIdx.y;
    const float* Wo = W_out + h * 65 * 65;
    for (int t = threadIdx.x; t < 4096; t += 256) {
        int k = t & 63, d = t >> 6;
        WoT[k * 64 + d] = Wo[(1 + d) * 65 + 1 + k];
    }
    __syncthreads();
    int wave = threadIdx.x >> 6, lane = threadIdx.x & 63;
    for (int nb = wave; nb < 64; nb += 4) {
        int i = blockIdx.x * 64 + nb;
        float lmreg = lm2[((size_t)h * N + i) * 64 + lane];
        float u = 0.f;
        #pragma unroll 8
        for (int k = 0; k < 64; k++) {
            u += __shfl(lmreg, k, 64) * WoT[k * 64 + lane];
        }
        float nv = fmaxf(sqrtf(wave_reduce_sum(u * u)), MINF);
        float sh = sinhf(nv), ch = coshf(nv);
        float ev = sh * u / nv;
        p[(size_t)i * 256 + h * 64 + lane] = ev / (ch + 1.0f);
    }
}

// ---------------- K6: final to_hyperboloid + logmap0 ----------------
__global__ void k_final_logmap(const float* __restrict__ p, float* __restrict__ lmF) {
    __shared__ float part[4];
    int i = blockIdx.x;
    int t = threadIdx.x;
    float pd = p[(size_t)i * 256 + t];
    float ss = wave_reduce_sum(pd * pd);
    if ((t & 63) == 0) part[t >> 6] = ss;
    __syncthreads();
    float s = part[0] + part[1] + part[2] + part[3];
    float Dh = fmaxf(1.0f - s, MINF);
    float hb0 = (1.0f + s) / Dh;
    float hbv = 2.0f * pd / Dh;
    float n = fmaxf(2.0f * sqrtf(s) / Dh, MINF);
    float tt = fmaxf(hb0, ONE_EPS);
    lmF[(size_t)i * 256 + t] = arcosh_f(tt) * hbv / n;
}

// ---------------- K7: final GEMM (N,256) @ (256,259) -> U (stride 260) -------
// U[i][o] = sum_k lmF[i][k] * W_lin[(1+o)*257 + (1+k)]
__global__ void k_final_gemm(const float* __restrict__ A,
                             const float* __restrict__ Wl,
                             float* __restrict__ U) {
    __shared__ float As[16][64];
    __shared__ float Bs[16][64];
    int i0 = blockIdx.x * 64;
    int o0 = blockIdx.y * 64;
    int tid = threadIdx.x;
    int tx = tid & 15, ty = tid >> 4;
    float acc[4][4] = {};
    for (int k0 = 0; k0 < 256; k0 += 16) {
        {
            int mm = tid >> 2;
            int kq = tid & 3;
            const float4 v = *(const float4*)(A + (size_t)(i0 + mm) * 256 + k0 + kq * 4);
            As[kq * 4 + 0][mm] = v.x;
            As[kq * 4 + 1][mm] = v.y;
            As[kq * 4 + 2][mm] = v.z;
            As[kq * 4 + 3][mm] = v.w;
        }
        {
            int oo = tid >> 2;
            int kq = tid & 3;
            int o = o0 + oo;
            if (o < 259) {
                const float* src = Wl + (size_t)(1 + o) * 257 + 1 + k0 + kq * 4;
                Bs[kq * 4 + 0][oo] = src[0];
                Bs[kq * 4 + 1][oo] = src[1];
                Bs[kq * 4 + 2][oo] = src[2];
                Bs[kq * 4 + 3][oo] = src[3];
            } else {
                Bs[kq * 4 + 0][oo] = 0.f;
                Bs[kq * 4 + 1][oo] = 0.f;
                Bs[kq * 4 + 2][oo] = 0.f;
                Bs[kq * 4 + 3][oo] = 0.f;
            }
        }
        __syncthreads();
        #pragma unroll
        for (int kk = 0; kk < 16; kk++) {
            float4 av = *(const float4*)&As[kk][ty * 4];
            float4 bv = *(const float4*)&Bs[kk][tx * 4];
            float a[4] = {av.x, av.y, av.z, av.w};
            float b[4] = {bv.x, bv.y, bv.z, bv.w};
            #pragma unroll
            for (int r = 0; r < 4; r++)
                #pragma unroll
                for (int c = 0; c < 4; c++) acc[r][c] += a[r] * b[c];
        }
        __syncthreads();
    }
    #pragma unroll
    for (int r = 0; r < 4; r++) {
        int i = i0 + ty * 4 + r;
        #pragma unroll
        for (int c = 0; c < 4; c++) {
            int o = o0 + tx * 4 + c;
            if (o < 259) U[(size_t)i * 260 + o] = acc[r][c];
        }
    }
}

// ---------------- K8: final expmap0 + hyp_proj epilogue ----------------
__global__ void k_final_epilogue(const float* __restrict__ U, float* __restrict__ out) {
    __shared__ float part[4];
    int i = blockIdx.x;
    int t = threadIdx.x;
    float a = U[(size_t)i * 260 + t];
    float b = (t < 3) ? U[(size_t)i * 260 + 256 + t] : 0.f;
    float ss = wave_reduce_sum(a * a + b * b);
    if ((t & 63) == 0) part[t >> 6] = ss;
    __syncthreads();
    ss = part[0] + part[1] + part[2] + part[3];
    float nv = fmaxf(sqrtf(ss), MINF);
    float sh = sinhf(nv);
    float scale = sh / nv;
    out[(size_t)i * 260 + 1 + t] = scale * a;
    if (t < 3) out[(size_t)i * 260 + 257 + t] = scale * b;
    if (t == 0) out[(size_t)i * 260] = sqrtf(1.0f + sh * sh);
}

extern "C" void kernel_launch(void* const* d_in, const int* in_sizes, int n_in,
                              void* d_out, int out_size, void* d_ws, size_t ws_size,
                              hipStream_t stream) {
    const float* x = (const float*)d_in[0];
    const float* adj = (const float*)d_in[1];
    const float* W_att = (const float*)d_in[2];
    const float* W_data = (const float*)d_in[3];
    const float* W_out = (const float*)d_in[4];
    const float* W_lin = (const float*)d_in[5];
    float* out = (float*)d_out;

    char* ws = (char*)d_ws;
    size_t off = 0;
    auto alloc = [&](size_t bytes) {
        void* ptr = ws + off;
        off += (bytes + 255) & ~(size_t)255;
        return ptr;
    };
    int* cnt = (int*)alloc((size_t)N * 4);
    int* idx = (int*)alloc((size_t)N * CAP * 4);
    float* lmv = (float*)alloc((size_t)N * 64 * 4);
    float* att0 = (float*)alloc((size_t)H * N * 4);
    float* attv = (float*)alloc((size_t)H * N * 64 * 4);
    float* pvb = (float*)alloc((size_t)H * N * 64 * 4);
    float* lam = (float*)alloc((size_t)H * N * 4);
    float* lm2 = (float*)alloc((size_t)H * N * 64 * 4);
    float* p = (float*)alloc((size_t)N * 256 * 4);
    float* lmF = (float*)alloc((size_t)N * 256 * 4);
    float* U = (float*)alloc((size_t)N * 260 * 4);

    hipMemsetAsync(cnt, 0, (size_t)N * 4, stream);
    k_build_csr<<<4096, 256, 0, stream>>>(adj, cnt, idx);
    k_logmap_x<<<N / 4, 256, 0, stream>>>(x, lmv);
    k_head_linear<<<dim3(N / 64, H), 256, 0, stream>>>(lmv, W_att, W_data, att0, attv, pvb, lam);
    k_attn_agg<<<dim3(N / 4, H), 256, 0, stream>>>(cnt, idx, att0, attv, pvb, lam, lm2);
    k_out_linear<<<dim3(N / 64, H), 256, 0, stream>>>(lm2, W_out, p);
    k_final_logmap<<<N, 256, 0, stream>>>(p, lmF);
    k_final_gemm<<<dim3(N / 64, 5), 256, 0, stream>>>(lmF, W_lin, U);
    k_final_epilogue<<<N, 256, 0, stream>>>(U, out);
}

// Round 2
// 385.728 us; speedup vs baseline: 1.3013x; 1.3013x over previous
//
#include <hip/hip_runtime.h>
#include <math.h>

#define N 6144
#define H 4
#define CAP 128       // max neighbors per row (binomial mean ~33, 128 is ~17 sigma)
#define MINF 1e-15f
#define ONE_EPS  1.0000001192092896f   // fp32(1.0 + 1e-7)
#define ONE_MEPS 0.9999998807907104f   // fp32(1.0 - 1e-7)

__device__ __forceinline__ float wave_reduce_sum(float v) {
    v += __shfl_xor(v, 32, 64);
    v += __shfl_xor(v, 16, 64);
    v += __shfl_xor(v, 8, 64);
    v += __shfl_xor(v, 4, 64);
    v += __shfl_xor(v, 2, 64);
    v += __shfl_xor(v, 1, 64);
    return v;
}

__device__ __forceinline__ float arcosh_f(float z) {
    return logf(z + sqrtf(fmaxf(z * z - 1.0f, 0.0f)));
}

// ---------------- K1: build CSR of adj^T ----------------
__global__ void k_build_csr(const float* __restrict__ adj,
                            int* __restrict__ cnt, int* __restrict__ idx) {
    const unsigned total4 = (unsigned)N * N / 4;
    const float4* a4 = (const float4*)adj;
    for (unsigned e = blockIdx.x * blockDim.x + threadIdx.x; e < total4;
         e += gridDim.x * blockDim.x) {
        float4 v = a4[e];
        unsigned base = e * 4u;
        float vals[4] = {v.x, v.y, v.z, v.w};
        #pragma unroll
        for (int q = 0; q < 4; q++) {
            if (vals[q] > 0.01f) {
                unsigned t = base + q;
                int j = t / N;
                int i = t % N;
                int pos = atomicAdd(&cnt[i], 1);
                if (pos < CAP) idx[i * CAP + pos] = j;
            }
        }
    }
}

// ---------------- K2: logmap0 of x (vector part only) ----------------
__global__ void k_logmap_x(const float* __restrict__ x, float* __restrict__ lmv) {
    int i = blockIdx.x * 4 + (threadIdx.x >> 6);
    int lane = threadIdx.x & 63;
    float y = x[i * 65 + 1 + lane];
    float ss = wave_reduce_sum(y * y);
    float n = fmaxf(sqrtf(ss), MINF);
    float t = fmaxf(x[i * 65], ONE_EPS);
    lmv[i * 64 + lane] = arcosh_f(t) * y / n;
}

// ---------------- K3: pack transposed weight blocks ----------------
// Bp: 8 mats (0..3 W_att, 4..7 W_data), Bo: 4 mats (W_out). layout [mat][k][o].
__global__ void k_pack(const float* __restrict__ W_att, const float* __restrict__ W_data,
                       const float* __restrict__ W_out,
                       float* __restrict__ Bp, float* __restrict__ Bo) {
    int tid = blockIdx.x * 256 + threadIdx.x;
    if (tid >= 12 * 4096) return;
    int m = tid >> 12;
    int r = tid & 4095;
    int k = r >> 6, o = r & 63;
    const float* src;
    if (m < 4) src = W_att + m * 65 * 65;
    else if (m < 8) src = W_data + (m - 4) * 65 * 65;
    else src = W_out + (m - 8) * 65 * 65;
    float val = src[(1 + o) * 65 + (1 + k)];
    if (m < 8) Bp[m * 4096 + k * 64 + o] = val;
    else Bo[(m - 8) * 4096 + k * 64 + o] = val;
}

// ---------------- K4: generic 64-wide GEMM: C[:, y*64..] = A_y (Nx64) @ B_y (64x64)
__global__ void k_gemm64(const float* __restrict__ A, size_t aStrideY,
                         const float* __restrict__ Bp, float* __restrict__ C, int ldc) {
    __shared__ float As[16][64];
    __shared__ float Bs[16][64];
    const float* Ab = A + aStrideY * blockIdx.y;
    const float* Bb = Bp + (size_t)blockIdx.y * 4096;
    int i0 = blockIdx.x * 64;
    int ocol = blockIdx.y * 64;
    int tid = threadIdx.x;
    int tx = tid & 15, ty = tid >> 4;
    float acc[4][4] = {};
    for (int k0 = 0; k0 < 64; k0 += 16) {
        {
            int mm = tid >> 2, kq = tid & 3;
            float4 v = *(const float4*)(Ab + (size_t)(i0 + mm) * 64 + k0 + kq * 4);
            As[kq * 4 + 0][mm] = v.x;
            As[kq * 4 + 1][mm] = v.y;
            As[kq * 4 + 2][mm] = v.z;
            As[kq * 4 + 3][mm] = v.w;
        }
        {
            int kk = tid >> 4, o4 = tid & 15;
            float4 bvv = *(const float4*)(Bb + (k0 + kk) * 64 + o4 * 4);
            *(float4*)&Bs[kk][o4 * 4] = bvv;
        }
        __syncthreads();
        #pragma unroll
        for (int kk = 0; kk < 16; kk++) {
            float4 av = *(const float4*)&As[kk][ty * 4];
            float4 bv = *(const float4*)&Bs[kk][tx * 4];
            float a[4] = {av.x, av.y, av.z, av.w};
            float b[4] = {bv.x, bv.y, bv.z, bv.w};
            #pragma unroll
            for (int r = 0; r < 4; r++)
                #pragma unroll
                for (int c = 0; c < 4; c++) acc[r][c] += a[r] * b[c];
        }
        __syncthreads();
    }
    #pragma unroll
    for (int r = 0; r < 4; r++) {
        int i = i0 + ty * 4 + r;
        #pragma unroll
        for (int c = 0; c < 4; c++)
            C[(size_t)i * ldc + ocol + tx * 4 + c] = acc[r][c];
    }
}

// ---------------- K5: head-linear epilogue: UAUD -> attv, att0, pv, lam ----------
__global__ void k_head_epi(const float* __restrict__ UAUD,
                           float* __restrict__ attv, float* __restrict__ att0,
                           float* __restrict__ pv, float* __restrict__ lam) {
    int i = blockIdx.x;
    int t = threadIdx.x;
    int h = t >> 6, lane = t & 63;
    float ua = UAUD[(size_t)i * 512 + t];
    float ud = UAUD[(size_t)i * 512 + 256 + t];
    float na = fmaxf(sqrtf(wave_reduce_sum(ua * ua)), MINF);
    float sha = sinhf(na);
    attv[((size_t)h * N + i) * 64 + lane] = sha * ua / na;
    if (lane == 0) att0[h * N + i] = coshf(na);
    float nd = fmaxf(sqrtf(wave_reduce_sum(ud * ud)), MINF);
    float shd = sinhf(nd), chd = coshf(nd);
    float pvd = (shd * ud / nd) / (chd + 1.0f);
    pv[((size_t)h * N + i) * 64 + lane] = pvd;
    float sp = wave_reduce_sum(pvd * pvd);
    if (lane == 0) lam[h * N + i] = 2.0f / fmaxf(1.0f - sp, MINF);
}

// ---------------- K6: fused sparse attention (scores lane=neighbor, agg lane=dim) --
__global__ void k_attn(const int* __restrict__ cnt, const int* __restrict__ idx,
                       const float* __restrict__ att0, const float* __restrict__ attv,
                       const float* __restrict__ pv, const float* __restrict__ lam,
                       float* __restrict__ lm2) {
    __shared__ float ai[4][64];
    __shared__ float wls[4][CAP];
    __shared__ int jls[4][CAP];
    int w = threadIdx.x >> 6, lane = threadIdx.x & 63;
    int i = blockIdx.x * 4 + w;
    int h = blockIdx.y;
    const float* attvh = attv + (size_t)h * N * 64;
    const float* pvh = pv + (size_t)h * N * 64;

    ai[w][lane] = attvh[(size_t)i * 64 + lane];
    __syncthreads();

    float ai0 = att0[h * N + i];
    int nn = min(cnt[i], CAP);
    float accd = 0.f, accss = 0.f;
    const float4* aiv4 = (const float4*)ai[w];
    for (int base = 0; base < nn; base += 64) {
        int t = base + lane;
        bool act = t < nn;
        int j = act ? idx[i * CAP + t] : i;
        float aj0 = att0[h * N + j];
        float lj = lam[h * N + j];
        const float4* bj = (const float4*)(attvh + (size_t)j * 64);
        float d0 = 0.f, d1 = 0.f, d2 = 0.f, d3 = 0.f;
        #pragma unroll
        for (int q = 0; q < 16; q++) {
            float4 a = aiv4[q];
            float4 b = bj[q];
            d0 += a.x * b.x; d1 += a.y * b.y; d2 += a.z * b.z; d3 += a.w * b.w;
        }
        float dot = (d0 + d1) + (d2 + d3);
        float theta = fmaxf(ai0 * aj0 - dot, ONE_EPS);
        float ar = arcosh_f(theta);
        float S = fminf(ar * ar, 50.0f);
        if (!act) S = 0.f;
        accd += S * (lj - 1.0f);
        accss += S * S;
        wls[w][t] = S * lj;
        jls[w][t] = j;
    }
    accd = wave_reduce_sum(accd);
    accss = wave_reduce_sum(accss);
    float nrm = fmaxf(sqrtf(accss), 1e-12f);
    float den = fmaxf(accd / nrm, MINF);
    float scl = 1.0f / (nrm * den);
    __syncthreads();

    // phase B: lane = dim
    float accn = 0.f;
    #pragma unroll 4
    for (int t = 0; t < nn; t++) {
        int j = jls[w][t];
        float wq = wls[w][t];
        accn = fmaf(wq, pvh[(size_t)j * 64 + lane], accn);
    }
    float v = -scl * accn;
    float nv = fmaxf(sqrtf(wave_reduce_sum(v * v)), MINF);
    float nc = fminf(nv, ONE_MEPS);
    float mh = tanhf(0.5f * atanhf(nc));
    float md = mh * v / nv;
    float s = wave_reduce_sum(md * md);
    float Dh = fmaxf(1.0f - s, MINF);
    float hb0 = (1.0f + s) / Dh;
    float hbv = 2.0f * md / Dh;
    float nh = fmaxf(2.0f * sqrtf(s) / Dh, MINF);
    float t2 = fmaxf(hb0, ONE_EPS);
    lm2[((size_t)h * N + i) * 64 + lane] = arcosh_f(t2) * hbv / nh;
}

// ---------------- K7: out-linear epilogue fused with final logmap ----------------
__global__ void k_out_epi(const float* __restrict__ u2, float* __restrict__ lmF) {
    __shared__ float part[4];
    int i = blockIdx.x;
    int t = threadIdx.x;
    int w = t >> 6;
    float u = u2[(size_t)i * 256 + t];
    float nv = fmaxf(sqrtf(wave_reduce_sum(u * u)), MINF);
    float sh = sinhf(nv), ch = coshf(nv);
    float pd = (sh * u / nv) / (ch + 1.0f);
    float ss = wave_reduce_sum(pd * pd);
    if ((t & 63) == 0) part[w] = ss;
    __syncthreads();
    float s = part[0] + part[1] + part[2] + part[3];
    float Dh = fmaxf(1.0f - s, MINF);
    float hb0 = (1.0f + s) / Dh;
    float hbv = 2.0f * pd / Dh;
    float n = fmaxf(2.0f * sqrtf(s) / Dh, MINF);
    float tt = fmaxf(hb0, ONE_EPS);
    lmF[(size_t)i * 256 + t] = arcosh_f(tt) * hbv / n;
}

// ---------------- K8: final GEMM (N,256) @ (256,259) -> U (stride 260) -------
__global__ void k_final_gemm(const float* __restrict__ A,
                             const float* __restrict__ Wl,
                             float* __restrict__ U) {
    __shared__ float As[16][64];
    __shared__ float Bs[16][64];
    int i0 = blockIdx.x * 64;
    int o0 = blockIdx.y * 64;
    int tid = threadIdx.x;
    int tx = tid & 15, ty = tid >> 4;
    float acc[4][4] = {};
    for (int k0 = 0; k0 < 256; k0 += 16) {
        {
            int mm = tid >> 2;
            int kq = tid & 3;
            const float4 v = *(const float4*)(A + (size_t)(i0 + mm) * 256 + k0 + kq * 4);
            As[kq * 4 + 0][mm] = v.x;
            As[kq * 4 + 1][mm] = v.y;
            As[kq * 4 + 2][mm] = v.z;
            As[kq * 4 + 3][mm] = v.w;
        }
        {
            int oo = tid >> 2;
            int kq = tid & 3;
            int o = o0 + oo;
            if (o < 259) {
                const float* src = Wl + (size_t)(1 + o) * 257 + 1 + k0 + kq * 4;
                Bs[kq * 4 + 0][oo] = src[0];
                Bs[kq * 4 + 1][oo] = src[1];
                Bs[kq * 4 + 2][oo] = src[2];
                Bs[kq * 4 + 3][oo] = src[3];
            } else {
                Bs[kq * 4 + 0][oo] = 0.f;
                Bs[kq * 4 + 1][oo] = 0.f;
                Bs[kq * 4 + 2][oo] = 0.f;
                Bs[kq * 4 + 3][oo] = 0.f;
            }
        }
        __syncthreads();
        #pragma unroll
        for (int kk = 0; kk < 16; kk++) {
            float4 av = *(const float4*)&As[kk][ty * 4];
            float4 bv = *(const float4*)&Bs[kk][tx * 4];
            float a[4] = {av.x, av.y, av.z, av.w};
            float b[4] = {bv.x, bv.y, bv.z, bv.w};
            #pragma unroll
            for (int r = 0; r < 4; r++)
                #pragma unroll
                for (int c = 0; c < 4; c++) acc[r][c] += a[r] * b[c];
        }
        __syncthreads();
    }
    #pragma unroll
    for (int r = 0; r < 4; r++) {
        int i = i0 + ty * 4 + r;
        #pragma unroll
        for (int c = 0; c < 4; c++) {
            int o = o0 + tx * 4 + c;
            if (o < 259) U[(size_t)i * 260 + o] = acc[r][c];
        }
    }
}

// ---------------- K9: final expmap0 + hyp_proj epilogue ----------------
__global__ void k_final_epilogue(const float* __restrict__ U, float* __restrict__ out) {
    __shared__ float part[4];
    int i = blockIdx.x;
    int t = threadIdx.x;
    float a = U[(size_t)i * 260 + t];
    float b = (t < 3) ? U[(size_t)i * 260 + 256 + t] : 0.f;
    float ss = wave_reduce_sum(a * a + b * b);
    if ((t & 63) == 0) part[t >> 6] = ss;
    __syncthreads();
    ss = part[0] + part[1] + part[2] + part[3];
    float nv = fmaxf(sqrtf(ss), MINF);
    float sh = sinhf(nv);
    float scale = sh / nv;
    out[(size_t)i * 260 + 1 + t] = scale * a;
    if (t < 3) out[(size_t)i * 260 + 257 + t] = scale * b;
    if (t == 0) out[(size_t)i * 260] = sqrtf(1.0f + sh * sh);
}

extern "C" void kernel_launch(void* const* d_in, const int* in_sizes, int n_in,
                              void* d_out, int out_size, void* d_ws, size_t ws_size,
                              hipStream_t stream) {
    const float* x = (const float*)d_in[0];
    const float* adj = (const float*)d_in[1];
    const float* W_att = (const float*)d_in[2];
    const float* W_data = (const float*)d_in[3];
    const float* W_out = (const float*)d_in[4];
    const float* W_lin = (const float*)d_in[5];
    float* out = (float*)d_out;

    char* ws = (char*)d_ws;
    size_t off = 0;
    auto alloc = [&](size_t bytes) {
        void* ptr = ws + off;
        off += (bytes + 255) & ~(size_t)255;
        return ptr;
    };
    int* cnt = (int*)alloc((size_t)N * 4);
    int* idx = (int*)alloc((size_t)N * CAP * 4);
    float* lmv = (float*)alloc((size_t)N * 64 * 4);
    float* UAUD = (float*)alloc((size_t)N * 512 * 4);   // reused as U (N*260) later
    float* attv = (float*)alloc((size_t)H * N * 64 * 4); // reused as lmF (N*256) later
    float* att0 = (float*)alloc((size_t)H * N * 4);
    float* pvb = (float*)alloc((size_t)H * N * 64 * 4);  // reused as u2 (N*256) later
    float* lam = (float*)alloc((size_t)H * N * 4);
    float* lm2 = (float*)alloc((size_t)H * N * 64 * 4);
    float* Bp = (float*)alloc((size_t)8 * 4096 * 4);
    float* Bo = (float*)alloc((size_t)4 * 4096 * 4);
    float* U = UAUD;     // alias: UAUD dead after k_head_epi
    float* lmF = attv;   // alias: attv dead after k_attn
    float* u2 = pvb;     // alias: pv dead after k_attn

    hipMemsetAsync(cnt, 0, (size_t)N * 4, stream);
    k_build_csr<<<4096, 256, 0, stream>>>(adj, cnt, idx);
    k_logmap_x<<<N / 4, 256, 0, stream>>>(x, lmv);
    k_pack<<<192, 256, 0, stream>>>(W_att, W_data, W_out, Bp, Bo);
    k_gemm64<<<dim3(N / 64, 8), 256, 0, stream>>>(lmv, 0, Bp, UAUD, 512);
    k_head_epi<<<N, 256, 0, stream>>>(UAUD, attv, att0, pvb, lam);
    k_attn<<<dim3(N / 4, H), 256, 0, stream>>>(cnt, idx, att0, attv, pvb, lam, lm2);
    k_gemm64<<<dim3(N / 64, 4), 256, 0, stream>>>(lm2, (size_t)N * 64, Bo, u2, 256);
    k_out_epi<<<N, 256, 0, stream>>>(u2, lmF);
    k_final_gemm<<<dim3(N / 64, 5), 256, 0, stream>>>(lmF, W_lin, U);
    k_final_epilogue<<<N, 256, 0, stream>>>(U, out);
}

// Round 3
// 351.351 us; speedup vs baseline: 1.4287x; 1.0978x over previous
//
#include <hip/hip_runtime.h>
#include <math.h>

#define N 6144
#define H 4
#define CAP 128       // max neighbors per row (binomial mean ~33, 128 is ~17 sigma)
#define MINF 1e-15f
#define ONE_EPS  1.0000001192092896f   // fp32(1.0 + 1e-7)
#define ONE_MEPS 0.9999998807907104f   // fp32(1.0 - 1e-7)

__device__ __forceinline__ float wave_reduce_sum(float v) {
    v += __shfl_xor(v, 32, 64);
    v += __shfl_xor(v, 16, 64);
    v += __shfl_xor(v, 8, 64);
    v += __shfl_xor(v, 4, 64);
    v += __shfl_xor(v, 2, 64);
    v += __shfl_xor(v, 1, 64);
    return v;
}

__device__ __forceinline__ float arcosh_f(float z) {
    return logf(z + sqrtf(fmaxf(z * z - 1.0f, 0.0f)));
}

// ---------------- K1: prep = logmap0(x) + weight pack + cnt zero ----------------
// blocks [0,1536): logmap (4 nodes each); [1536,1728): pack; [1728,1752): zero cnt
__global__ void k_prep(const float* __restrict__ x, float* __restrict__ lmv,
                       const float* __restrict__ W_att, const float* __restrict__ W_data,
                       const float* __restrict__ W_out,
                       float* __restrict__ Bp, float* __restrict__ Bo,
                       int* __restrict__ cnt) {
    int b = blockIdx.x;
    if (b < 1536) {
        int i = b * 4 + (threadIdx.x >> 6);
        int lane = threadIdx.x & 63;
        float y = x[i * 65 + 1 + lane];
        float ss = wave_reduce_sum(y * y);
        float n = fmaxf(sqrtf(ss), MINF);
        float t = fmaxf(x[i * 65], ONE_EPS);
        lmv[i * 64 + lane] = arcosh_f(t) * y / n;
    } else if (b < 1728) {
        int tid = (b - 1536) * 256 + threadIdx.x;
        int m = tid >> 12;
        int r = tid & 4095;
        int k = r >> 6, o = r & 63;
        const float* src;
        if (m < 4) src = W_att + m * 65 * 65;
        else if (m < 8) src = W_data + (m - 4) * 65 * 65;
        else src = W_out + (m - 8) * 65 * 65;
        float val = src[(1 + o) * 65 + (1 + k)];
        if (m < 8) Bp[m * 4096 + k * 64 + o] = val;
        else Bo[(m - 8) * 4096 + k * 64 + o] = val;
    } else {
        cnt[(b - 1728) * 256 + threadIdx.x] = 0;
    }
}

// ---------------- K2: build CSR of adj^T ----------------
__global__ void k_build_csr(const float* __restrict__ adj,
                            int* __restrict__ cnt, int* __restrict__ idx) {
    const unsigned total4 = (unsigned)N * N / 4;
    const float4* a4 = (const float4*)adj;
    for (unsigned e = blockIdx.x * blockDim.x + threadIdx.x; e < total4;
         e += gridDim.x * blockDim.x) {
        float4 v = a4[e];
        unsigned base = e * 4u;
        float vals[4] = {v.x, v.y, v.z, v.w};
        #pragma unroll
        for (int q = 0; q < 4; q++) {
            if (vals[q] > 0.01f) {
                unsigned t = base + q;
                int j = t / N;
                int i = t % N;
                int pos = atomicAdd(&cnt[i], 1);
                if (pos < CAP) idx[i * CAP + pos] = j;
            }
        }
    }
}

// ---------------- K3: generic 64-wide GEMM: C[:, y*64..] = A_y (Nx64) @ B_y (64x64)
__global__ void k_gemm64(const float* __restrict__ A, size_t aStrideY,
                         const float* __restrict__ Bp, float* __restrict__ C, int ldc) {
    __shared__ float As[16][64];
    __shared__ float Bs[16][64];
    const float* Ab = A + aStrideY * blockIdx.y;
    const float* Bb = Bp + (size_t)blockIdx.y * 4096;
    int i0 = blockIdx.x * 64;
    int ocol = blockIdx.y * 64;
    int tid = threadIdx.x;
    int tx = tid & 15, ty = tid >> 4;
    float acc[4][4] = {};
    for (int k0 = 0; k0 < 64; k0 += 16) {
        {
            int mm = tid >> 2, kq = tid & 3;
            float4 v = *(const float4*)(Ab + (size_t)(i0 + mm) * 64 + k0 + kq * 4);
            As[kq * 4 + 0][mm] = v.x;
            As[kq * 4 + 1][mm] = v.y;
            As[kq * 4 + 2][mm] = v.z;
            As[kq * 4 + 3][mm] = v.w;
        }
        {
            int kk = tid >> 4, o4 = tid & 15;
            float4 bvv = *(const float4*)(Bb + (k0 + kk) * 64 + o4 * 4);
            *(float4*)&Bs[kk][o4 * 4] = bvv;
        }
        __syncthreads();
        #pragma unroll
        for (int kk = 0; kk < 16; kk++) {
            float4 av = *(const float4*)&As[kk][ty * 4];
            float4 bv = *(const float4*)&Bs[kk][tx * 4];
            float a[4] = {av.x, av.y, av.z, av.w};
            float b[4] = {bv.x, bv.y, bv.z, bv.w};
            #pragma unroll
            for (int r = 0; r < 4; r++)
                #pragma unroll
                for (int c = 0; c < 4; c++) acc[r][c] += a[r] * b[c];
        }
        __syncthreads();
    }
    #pragma unroll
    for (int r = 0; r < 4; r++) {
        int i = i0 + ty * 4 + r;
        #pragma unroll
        for (int c = 0; c < 4; c++)
            C[(size_t)i * ldc + ocol + tx * 4 + c] = acc[r][c];
    }
}

// ---------------- K4: head-linear epilogue: UAUD -> attv, a0l(att0,lam), pv -------
__global__ void k_head_epi(const float* __restrict__ UAUD,
                           float* __restrict__ attv, float2* __restrict__ a0l,
                           float* __restrict__ pv) {
    int i = blockIdx.x;
    int t = threadIdx.x;
    int h = t >> 6, lane = t & 63;
    float ua = UAUD[(size_t)i * 512 + t];
    float ud = UAUD[(size_t)i * 512 + 256 + t];
    float na = fmaxf(sqrtf(wave_reduce_sum(ua * ua)), MINF);
    float sha = sinhf(na);
    attv[((size_t)h * N + i) * 64 + lane] = sha * ua / na;
    float nd = fmaxf(sqrtf(wave_reduce_sum(ud * ud)), MINF);
    float shd = sinhf(nd), chd = coshf(nd);
    float pvd = (shd * ud / nd) / (chd + 1.0f);
    pv[((size_t)h * N + i) * 64 + lane] = pvd;
    float sp = wave_reduce_sum(pvd * pvd);
    if (lane == 0) {
        a0l[h * N + i] = make_float2(coshf(na), 2.0f / fmaxf(1.0f - sp, MINF));
    }
}

// ---------------- K5: fused sparse attention ----------------
// Phase A: quad of lanes per neighbor (each lane 16 dims -> 1 line/quad/instr).
// Phase B: lane = dim, coalesced pv rows.
__global__ void __launch_bounds__(256) k_attn(
        const int* __restrict__ cnt, const int* __restrict__ idx,
        const float* __restrict__ attv, const float2* __restrict__ a0l,
        const float* __restrict__ pv, float* __restrict__ lm2) {
    __shared__ float wls[4][CAP];
    __shared__ int jls[4][CAP];
    int w = threadIdx.x >> 6, lane = threadIdx.x & 63;
    int i = blockIdx.x * 4 + w;
    int h = blockIdx.y;
    const float* attvh = attv + (size_t)h * N * 64;
    const float* pvh = pv + (size_t)h * N * 64;
    const float2* a0lh = a0l + (size_t)h * N;

    int c = lane & 3;
    // this lane's 16 dims of a_i: dims {q*16 + c*4 .. +3}
    float4 aireg[4];
    #pragma unroll
    for (int q = 0; q < 4; q++)
        aireg[q] = *(const float4*)(attvh + (size_t)i * 64 + q * 16 + c * 4);
    float ai0 = a0lh[i].x;
    int nn = min(cnt[i], CAP);

    float accd = 0.f, accss = 0.f;
    for (int base = 0; base < nn; base += 16) {
        int t = base + (lane >> 2);
        bool act = t < nn;
        int j = act ? idx[i * CAP + t] : i;
        float2 al = a0lh[j];
        float d = 0.f;
        #pragma unroll
        for (int q = 0; q < 4; q++) {
            float4 b = *(const float4*)(attvh + (size_t)j * 64 + q * 16 + c * 4);
            float4 a = aireg[q];
            d += a.x * b.x + a.y * b.y + a.z * b.z + a.w * b.w;
        }
        d += __shfl_xor(d, 1, 64);
        d += __shfl_xor(d, 2, 64);
        float theta = fmaxf(ai0 * al.x - d, ONE_EPS);
        float ar = arcosh_f(theta);
        float S = fminf(ar * ar, 50.0f);
        if (!act) S = 0.f;
        if (c == 0) {
            accd += S * (al.y - 1.0f);
            accss += S * S;
            wls[w][t] = S * al.y;
            jls[w][t] = j;
        }
    }
    accd = wave_reduce_sum(accd);
    accss = wave_reduce_sum(accss);
    float nrm = fmaxf(sqrtf(accss), 1e-12f);
    float den = fmaxf(accd / nrm, MINF);
    float scl = 1.0f / (nrm * den);

    // phase B: lane = dim (wls/jls are wave-private: no barrier needed)
    float accn = 0.f;
    #pragma unroll 4
    for (int t = 0; t < nn; t++) {
        int j = jls[w][t];
        float wq = wls[w][t];
        accn = fmaf(wq, pvh[(size_t)j * 64 + lane], accn);
    }
    float v = -scl * accn;
    float nv = fmaxf(sqrtf(wave_reduce_sum(v * v)), MINF);
    float nc = fminf(nv, ONE_MEPS);
    float mh = tanhf(0.5f * atanhf(nc));
    float md = mh * v / nv;
    float s = wave_reduce_sum(md * md);
    float Dh = fmaxf(1.0f - s, MINF);
    float hb0 = (1.0f + s) / Dh;
    float hbv = 2.0f * md / Dh;
    float nh = fmaxf(2.0f * sqrtf(s) / Dh, MINF);
    float t2 = fmaxf(hb0, ONE_EPS);
    lm2[((size_t)h * N + i) * 64 + lane] = arcosh_f(t2) * hbv / nh;
}

// ---------------- K6: out-linear epilogue fused with final logmap ----------------
__global__ void k_out_epi(const float* __restrict__ u2, float* __restrict__ lmF) {
    __shared__ float part[4];
    int i = blockIdx.x;
    int t = threadIdx.x;
    int w = t >> 6;
    float u = u2[(size_t)i * 256 + t];
    float nv = fmaxf(sqrtf(wave_reduce_sum(u * u)), MINF);
    float sh = sinhf(nv), ch = coshf(nv);
    float pd = (sh * u / nv) / (ch + 1.0f);
    float ss = wave_reduce_sum(pd * pd);
    if ((t & 63) == 0) part[w] = ss;
    __syncthreads();
    float s = part[0] + part[1] + part[2] + part[3];
    float Dh = fmaxf(1.0f - s, MINF);
    float hb0 = (1.0f + s) / Dh;
    float hbv = 2.0f * pd / Dh;
    float n = fmaxf(2.0f * sqrtf(s) / Dh, MINF);
    float tt = fmaxf(hb0, ONE_EPS);
    lmF[(size_t)i * 256 + t] = arcosh_f(tt) * hbv / n;
}

// ---------------- K7: final GEMM (N,256) @ (256,259) -> U (stride 260) -------
__global__ void k_final_gemm(const float* __restrict__ A,
                             const float* __restrict__ Wl,
                             float* __restrict__ U) {
    __shared__ float As[16][64];
    __shared__ float Bs[16][64];
    int i0 = blockIdx.x * 64;
    int o0 = blockIdx.y * 64;
    int tid = threadIdx.x;
    int tx = tid & 15, ty = tid >> 4;
    float acc[4][4] = {};
    for (int k0 = 0; k0 < 256; k0 += 16) {
        {
            int mm = tid >> 2;
            int kq = tid & 3;
            const float4 v = *(const float4*)(A + (size_t)(i0 + mm) * 256 + k0 + kq * 4);
            As[kq * 4 + 0][mm] = v.x;
            As[kq * 4 + 1][mm] = v.y;
            As[kq * 4 + 2][mm] = v.z;
            As[kq * 4 + 3][mm] = v.w;
        }
        {
            int oo = tid >> 2;
            int kq = tid & 3;
            int o = o0 + oo;
            if (o < 259) {
                const float* src = Wl + (size_t)(1 + o) * 257 + 1 + k0 + kq * 4;
                Bs[kq * 4 + 0][oo] = src[0];
                Bs[kq * 4 + 1][oo] = src[1];
                Bs[kq * 4 + 2][oo] = src[2];
                Bs[kq * 4 + 3][oo] = src[3];
            } else {
                Bs[kq * 4 + 0][oo] = 0.f;
                Bs[kq * 4 + 1][oo] = 0.f;
                Bs[kq * 4 + 2][oo] = 0.f;
                Bs[kq * 4 + 3][oo] = 0.f;
            }
        }
        __syncthreads();
        #pragma unroll
        for (int kk = 0; kk < 16; kk++) {
            float4 av = *(const float4*)&As[kk][ty * 4];
            float4 bv = *(const float4*)&Bs[kk][tx * 4];
            float a[4] = {av.x, av.y, av.z, av.w};
            float b[4] = {bv.x, bv.y, bv.z, bv.w};
            #pragma unroll
            for (int r = 0; r < 4; r++)
                #pragma unroll
                for (int c = 0; c < 4; c++) acc[r][c] += a[r] * b[c];
        }
        __syncthreads();
    }
    #pragma unroll
    for (int r = 0; r < 4; r++) {
        int i = i0 + ty * 4 + r;
        #pragma unroll
        for (int c = 0; c < 4; c++) {
            int o = o0 + tx * 4 + c;
            if (o < 259) U[(size_t)i * 260 + o] = acc[r][c];
        }
    }
}

// ---------------- K8: final expmap0 + hyp_proj epilogue ----------------
__global__ void k_final_epilogue(const float* __restrict__ U, float* __restrict__ out) {
    __shared__ float part[4];
    int i = blockIdx.x;
    int t = threadIdx.x;
    float a = U[(size_t)i * 260 + t];
    float b = (t < 3) ? U[(size_t)i * 260 + 256 + t] : 0.f;
    float ss = wave_reduce_sum(a * a + b * b);
    if ((t & 63) == 0) part[t >> 6] = ss;
    __syncthreads();
    ss = part[0] + part[1] + part[2] + part[3];
    float nv = fmaxf(sqrtf(ss), MINF);
    float sh = sinhf(nv);
    float scale = sh / nv;
    out[(size_t)i * 260 + 1 + t] = scale * a;
    if (t < 3) out[(size_t)i * 260 + 257 + t] = scale * b;
    if (t == 0) out[(size_t)i * 260] = sqrtf(1.0f + sh * sh);
}

extern "C" void kernel_launch(void* const* d_in, const int* in_sizes, int n_in,
                              void* d_out, int out_size, void* d_ws, size_t ws_size,
                              hipStream_t stream) {
    const float* x = (const float*)d_in[0];
    const float* adj = (const float*)d_in[1];
    const float* W_att = (const float*)d_in[2];
    const float* W_data = (const float*)d_in[3];
    const float* W_out = (const float*)d_in[4];
    const float* W_lin = (const float*)d_in[5];
    float* out = (float*)d_out;

    char* ws = (char*)d_ws;
    size_t off = 0;
    auto alloc = [&](size_t bytes) {
        void* ptr = ws + off;
        off += (bytes + 255) & ~(size_t)255;
        return ptr;
    };
    int* cnt = (int*)alloc((size_t)N * 4);
    int* idx = (int*)alloc((size_t)N * CAP * 4);
    float* lmv = (float*)alloc((size_t)N * 64 * 4);
    float* UAUD = (float*)alloc((size_t)N * 512 * 4);    // reused as U (N*260) later
    float* attv = (float*)alloc((size_t)H * N * 64 * 4); // reused as lmF (N*256) later
    float2* a0l = (float2*)alloc((size_t)H * N * 8);
    float* pvb = (float*)alloc((size_t)H * N * 64 * 4);  // reused as u2 (N*256) later
    float* lm2 = (float*)alloc((size_t)H * N * 64 * 4);
    float* Bp = (float*)alloc((size_t)8 * 4096 * 4);
    float* Bo = (float*)alloc((size_t)4 * 4096 * 4);
    float* U = UAUD;     // alias: UAUD dead after k_head_epi
    float* lmF = attv;   // alias: attv dead after k_attn
    float* u2 = pvb;     // alias: pv dead after k_attn

    k_prep<<<1752, 256, 0, stream>>>(x, lmv, W_att, W_data, W_out, Bp, Bo, cnt);
    k_build_csr<<<4096, 256, 0, stream>>>(adj, cnt, idx);
    k_gemm64<<<dim3(N / 64, 8), 256, 0, stream>>>(lmv, 0, Bp, UAUD, 512);
    k_head_epi<<<N, 256, 0, stream>>>(UAUD, attv, a0l, pvb);
    k_attn<<<dim3(N / 4, H), 256, 0, stream>>>(cnt, idx, attv, a0l, pvb, lm2);
    k_gemm64<<<dim3(N / 64, 4), 256, 0, stream>>>(lm2, (size_t)N * 64, Bo, u2, 256);
    k_out_epi<<<N, 256, 0, stream>>>(u2, lmF);
    k_final_gemm<<<dim3(N / 64, 5), 256, 0, stream>>>(lmF, W_lin, U);
    k_final_epilogue<<<N, 256, 0, stream>>>(U, out);
}

// Round 4
// 349.239 us; speedup vs baseline: 1.4373x; 1.0060x over previous
//
#include <hip/hip_runtime.h>
#include <math.h>

#define N 6144
#define H 4
#define CAP 128       // max neighbors per row (binomial mean ~33, 128 is ~17 sigma)
#define MINF 1e-15f
#define ONE_EPS  1.0000001192092896f   // fp32(1.0 + 1e-7)
#define ONE_MEPS 0.9999998807907104f   // fp32(1.0 - 1e-7)

__device__ __forceinline__ float wave_reduce_sum(float v) {
    v += __shfl_xor(v, 32, 64);
    v += __shfl_xor(v, 16, 64);
    v += __shfl_xor(v, 8, 64);
    v += __shfl_xor(v, 4, 64);
    v += __shfl_xor(v, 2, 64);
    v += __shfl_xor(v, 1, 64);
    return v;
}

__device__ __forceinline__ float arcosh_f(float z) {
    return logf(z + sqrtf(fmaxf(z * z - 1.0f, 0.0f)));
}

// ---------------- K1: prep = logmap0(x) + weight pack + cnt zero ----------------
__global__ void k_prep(const float* __restrict__ x, float* __restrict__ lmv,
                       const float* __restrict__ W_att, const float* __restrict__ W_data,
                       const float* __restrict__ W_out,
                       float* __restrict__ Bp, float* __restrict__ Bo,
                       int* __restrict__ cnt) {
    int b = blockIdx.x;
    if (b < 1536) {
        int i = b * 4 + (threadIdx.x >> 6);
        int lane = threadIdx.x & 63;
        float y = x[i * 65 + 1 + lane];
        float ss = wave_reduce_sum(y * y);
        float n = fmaxf(sqrtf(ss), MINF);
        float t = fmaxf(x[i * 65], ONE_EPS);
        lmv[i * 64 + lane] = arcosh_f(t) * y / n;
    } else if (b < 1728) {
        int tid = (b - 1536) * 256 + threadIdx.x;
        int m = tid >> 12;
        int r = tid & 4095;
        int k = r >> 6, o = r & 63;
        const float* src;
        if (m < 4) src = W_att + m * 65 * 65;
        else if (m < 8) src = W_data + (m - 4) * 65 * 65;
        else src = W_out + (m - 8) * 65 * 65;
        float val = src[(1 + o) * 65 + (1 + k)];
        if (m < 8) Bp[m * 4096 + k * 64 + o] = val;
        else Bo[(m - 8) * 4096 + k * 64 + o] = val;
    } else {
        cnt[(b - 1728) * 256 + threadIdx.x] = 0;
    }
}

// ---------------- K2: heterogeneous: GEMM1+head-epilogue || CSR build ----------
// blocks [0,768): 8 mats x 96 row-tiles of (N x 64)@(64 x 64) with fused expmap
// epilogue; blocks [768, 4864): grid-stride scan of adj building CSR of adj^T.
__global__ void __launch_bounds__(256) k_csr_gemm(
        const float* __restrict__ adj, int* __restrict__ cnt, int* __restrict__ idx,
        const float* __restrict__ lmv, const float* __restrict__ Bp,
        float* __restrict__ attv, float2* __restrict__ a0l, float* __restrict__ pv) {
    __shared__ float As[16][64];
    __shared__ float Bs[16][64];
    __shared__ float Cs[64][65];
    if (blockIdx.x < 768) {
        int my = blockIdx.x / 96;      // matrix: 0..3 W_att, 4..7 W_data
        int ix = blockIdx.x % 96;
        const float* Bb = Bp + (size_t)my * 4096;
        int i0 = ix * 64;
        int tid = threadIdx.x;
        int tx = tid & 15, ty = tid >> 4;
        float acc[4][4] = {};
        for (int k0 = 0; k0 < 64; k0 += 16) {
            {
                int mm = tid >> 2, kq = tid & 3;
                float4 v = *(const float4*)(lmv + (size_t)(i0 + mm) * 64 + k0 + kq * 4);
                As[kq * 4 + 0][mm] = v.x;
                As[kq * 4 + 1][mm] = v.y;
                As[kq * 4 + 2][mm] = v.z;
                As[kq * 4 + 3][mm] = v.w;
            }
            {
                int kk = tid >> 4, o4 = tid & 15;
                float4 bvv = *(const float4*)(Bb + (k0 + kk) * 64 + o4 * 4);
                *(float4*)&Bs[kk][o4 * 4] = bvv;
            }
            __syncthreads();
            #pragma unroll
            for (int kk = 0; kk < 16; kk++) {
                float4 av = *(const float4*)&As[kk][ty * 4];
                float4 bv = *(const float4*)&Bs[kk][tx * 4];
                float a[4] = {av.x, av.y, av.z, av.w};
                float b[4] = {bv.x, bv.y, bv.z, bv.w};
                #pragma unroll
                for (int r = 0; r < 4; r++)
                    #pragma unroll
                    for (int c = 0; c < 4; c++) acc[r][c] += a[r] * b[c];
            }
            __syncthreads();
        }
        #pragma unroll
        for (int r = 0; r < 4; r++)
            #pragma unroll
            for (int c = 0; c < 4; c++)
                Cs[ty * 4 + r][tx * 4 + c] = acc[r][c];
        __syncthreads();
        int w = tid >> 6, lane = tid & 63;
        int h = my & 3;
        bool isAtt = my < 4;
        #pragma unroll 1
        for (int r16 = 0; r16 < 16; r16++) {
            int row = w * 16 + r16;
            int i = i0 + row;
            float u = Cs[row][lane];
            float nn = fmaxf(sqrtf(wave_reduce_sum(u * u)), MINF);
            if (isAtt) {
                float sha = sinhf(nn);
                attv[((size_t)h * N + i) * 64 + lane] = sha * u / nn;
                if (lane == 0) a0l[h * N + i].x = coshf(nn);
            } else {
                float shd = sinhf(nn), chd = coshf(nn);
                float pvd = (shd * u / nn) / (chd + 1.0f);
                pv[((size_t)h * N + i) * 64 + lane] = pvd;
                float sp = wave_reduce_sum(pvd * pvd);
                if (lane == 0) a0l[h * N + i].y = 2.0f / fmaxf(1.0f - sp, MINF);
            }
        }
    } else {
        const unsigned total4 = (unsigned)N * N / 4;
        const float4* a4 = (const float4*)adj;
        for (unsigned e = (blockIdx.x - 768) * 256 + threadIdx.x; e < total4;
             e += 4096u * 256u) {
            float4 v = a4[e];
            unsigned base = e * 4u;
            float vals[4] = {v.x, v.y, v.z, v.w};
            #pragma unroll
            for (int q = 0; q < 4; q++) {
                if (vals[q] > 0.01f) {
                    unsigned t = base + q;
                    int j = t / N;
                    int i = t % N;
                    int pos = atomicAdd(&cnt[i], 1);
                    if (pos < CAP) idx[i * CAP + pos] = j;
                }
            }
        }
    }
}

// ---------------- K3: fused sparse attention ----------------
__global__ void __launch_bounds__(256) k_attn(
        const int* __restrict__ cnt, const int* __restrict__ idx,
        const float* __restrict__ attv, const float2* __restrict__ a0l,
        const float* __restrict__ pv, float* __restrict__ lm2) {
    __shared__ float wls[4][CAP];
    __shared__ int jls[4][CAP];
    int w = threadIdx.x >> 6, lane = threadIdx.x & 63;
    int i = blockIdx.x * 4 + w;
    int h = blockIdx.y;
    const float* attvh = attv + (size_t)h * N * 64;
    const float* pvh = pv + (size_t)h * N * 64;
    const float2* a0lh = a0l + (size_t)h * N;

    int c = lane & 3;
    float4 aireg[4];
    #pragma unroll
    for (int q = 0; q < 4; q++)
        aireg[q] = *(const float4*)(attvh + (size_t)i * 64 + q * 16 + c * 4);
    float ai0 = a0lh[i].x;
    int nn = min(cnt[i], CAP);

    float accd = 0.f, accss = 0.f;
    for (int base = 0; base < nn; base += 16) {
        int t = base + (lane >> 2);
        bool act = t < nn;
        int j = act ? idx[i * CAP + t] : i;
        float2 al = a0lh[j];
        float d = 0.f;
        #pragma unroll
        for (int q = 0; q < 4; q++) {
            float4 b = *(const float4*)(attvh + (size_t)j * 64 + q * 16 + c * 4);
            float4 a = aireg[q];
            d += a.x * b.x + a.y * b.y + a.z * b.z + a.w * b.w;
        }
        d += __shfl_xor(d, 1, 64);
        d += __shfl_xor(d, 2, 64);
        float theta = fmaxf(ai0 * al.x - d, ONE_EPS);
        float ar = arcosh_f(theta);
        float S = fminf(ar * ar, 50.0f);
        if (!act) S = 0.f;
        if (c == 0) {
            accd += S * (al.y - 1.0f);
            accss += S * S;
            wls[w][t] = S * al.y;
            jls[w][t] = j;
        }
    }
    accd = wave_reduce_sum(accd);
    accss = wave_reduce_sum(accss);
    float nrm = fmaxf(sqrtf(accss), 1e-12f);
    float den = fmaxf(accd / nrm, MINF);
    float scl = 1.0f / (nrm * den);

    float accn = 0.f;
    #pragma unroll 4
    for (int t = 0; t < nn; t++) {
        int j = jls[w][t];
        float wq = wls[w][t];
        accn = fmaf(wq, pvh[(size_t)j * 64 + lane], accn);
    }
    float v = -scl * accn;
    float nv = fmaxf(sqrtf(wave_reduce_sum(v * v)), MINF);
    float nc = fminf(nv, ONE_MEPS);
    float mh = tanhf(0.5f * atanhf(nc));
    float md = mh * v / nv;
    float s = wave_reduce_sum(md * md);
    float Dh = fmaxf(1.0f - s, MINF);
    float hb0 = (1.0f + s) / Dh;
    float hbv = 2.0f * md / Dh;
    float nh = fmaxf(2.0f * sqrtf(s) / Dh, MINF);
    float t2 = fmaxf(hb0, ONE_EPS);
    lm2[((size_t)h * N + i) * 64 + lane] = arcosh_f(t2) * hbv / nh;
}

// ---------------- K4: GEMM2 (per-head out linear) + expmap/to_poincare -> p -----
__global__ void __launch_bounds__(256) k_gemm_out(
        const float* __restrict__ lm2, const float* __restrict__ Bo,
        float* __restrict__ p) {
    __shared__ float As[16][64];
    __shared__ float Bs[16][64];
    __shared__ float Cs[64][65];
    int h = blockIdx.y;
    const float* Ab = lm2 + (size_t)h * N * 64;
    const float* Bb = Bo + (size_t)h * 4096;
    int i0 = blockIdx.x * 64;
    int tid = threadIdx.x;
    int tx = tid & 15, ty = tid >> 4;
    float acc[4][4] = {};
    for (int k0 = 0; k0 < 64; k0 += 16) {
        {
            int mm = tid >> 2, kq = tid & 3;
            float4 v = *(const float4*)(Ab + (size_t)(i0 + mm) * 64 + k0 + kq * 4);
            As[kq * 4 + 0][mm] = v.x;
            As[kq * 4 + 1][mm] = v.y;
            As[kq * 4 + 2][mm] = v.z;
            As[kq * 4 + 3][mm] = v.w;
        }
        {
            int kk = tid >> 4, o4 = tid & 15;
            float4 bvv = *(const float4*)(Bb + (k0 + kk) * 64 + o4 * 4);
            *(float4*)&Bs[kk][o4 * 4] = bvv;
        }
        __syncthreads();
        #pragma unroll
        for (int kk = 0; kk < 16; kk++) {
            float4 av = *(const float4*)&As[kk][ty * 4];
            float4 bv = *(const float4*)&Bs[kk][tx * 4];
            float a[4] = {av.x, av.y, av.z, av.w};
            float b[4] = {bv.x, bv.y, bv.z, bv.w};
            #pragma unroll
            for (int r = 0; r < 4; r++)
                #pragma unroll
                for (int c = 0; c < 4; c++) acc[r][c] += a[r] * b[c];
        }
        __syncthreads();
    }
    #pragma unroll
    for (int r = 0; r < 4; r++)
        #pragma unroll
        for (int c = 0; c < 4; c++)
            Cs[ty * 4 + r][tx * 4 + c] = acc[r][c];
    __syncthreads();
    int w = tid >> 6, lane = tid & 63;
    #pragma unroll 1
    for (int r16 = 0; r16 < 16; r16++) {
        int row = w * 16 + r16;
        int i = i0 + row;
        float u = Cs[row][lane];
        float nv = fmaxf(sqrtf(wave_reduce_sum(u * u)), MINF);
        float sh = sinhf(nv), ch = coshf(nv);
        p[(size_t)i * 256 + h * 64 + lane] = (sh * u / nv) / (ch + 1.0f);
    }
}

// ---------------- K5: final to_hyperboloid + logmap0 (256-dim) ----------------
__global__ void k_final_logmap(const float* __restrict__ p, float* __restrict__ lmF) {
    __shared__ float part[4];
    int i = blockIdx.x;
    int t = threadIdx.x;
    int w = t >> 6;
    float pd = p[(size_t)i * 256 + t];
    float ss = wave_reduce_sum(pd * pd);
    if ((t & 63) == 0) part[w] = ss;
    __syncthreads();
    float s = part[0] + part[1] + part[2] + part[3];
    float Dh = fmaxf(1.0f - s, MINF);
    float hb0 = (1.0f + s) / Dh;
    float hbv = 2.0f * pd / Dh;
    float n = fmaxf(2.0f * sqrtf(s) / Dh, MINF);
    float tt = fmaxf(hb0, ONE_EPS);
    lmF[(size_t)i * 256 + t] = arcosh_f(tt) * hbv / n;
}

// ---------------- K6: final GEMM (N,256) @ (256,259) -> U (stride 260) -------
__global__ void k_final_gemm(const float* __restrict__ A,
                             const float* __restrict__ Wl,
                             float* __restrict__ U) {
    __shared__ float As[16][64];
    __shared__ float Bs[16][64];
    int i0 = blockIdx.x * 64;
    int o0 = blockIdx.y * 64;
    int tid = threadIdx.x;
    int tx = tid & 15, ty = tid >> 4;
    float acc[4][4] = {};
    for (int k0 = 0; k0 < 256; k0 += 16) {
        {
            int mm = tid >> 2;
            int kq = tid & 3;
            const float4 v = *(const float4*)(A + (size_t)(i0 + mm) * 256 + k0 + kq * 4);
            As[kq * 4 + 0][mm] = v.x;
            As[kq * 4 + 1][mm] = v.y;
            As[kq * 4 + 2][mm] = v.z;
            As[kq * 4 + 3][mm] = v.w;
        }
        {
            int oo = tid >> 2;
            int kq = tid & 3;
            int o = o0 + oo;
            if (o < 259) {
                const float* src = Wl + (size_t)(1 + o) * 257 + 1 + k0 + kq * 4;
                Bs[kq * 4 + 0][oo] = src[0];
                Bs[kq * 4 + 1][oo] = src[1];
                Bs[kq * 4 + 2][oo] = src[2];
                Bs[kq * 4 + 3][oo] = src[3];
            } else {
                Bs[kq * 4 + 0][oo] = 0.f;
                Bs[kq * 4 + 1][oo] = 0.f;
                Bs[kq * 4 + 2][oo] = 0.f;
                Bs[kq * 4 + 3][oo] = 0.f;
            }
        }
        __syncthreads();
        #pragma unroll
        for (int kk = 0; kk < 16; kk++) {
            float4 av = *(const float4*)&As[kk][ty * 4];
            float4 bv = *(const float4*)&Bs[kk][tx * 4];
            float a[4] = {av.x, av.y, av.z, av.w};
            float b[4] = {bv.x, bv.y, bv.z, bv.w};
            #pragma unroll
            for (int r = 0; r < 4; r++)
                #pragma unroll
                for (int c = 0; c < 4; c++) acc[r][c] += a[r] * b[c];
        }
        __syncthreads();
    }
    #pragma unroll
    for (int r = 0; r < 4; r++) {
        int i = i0 + ty * 4 + r;
        #pragma unroll
        for (int c = 0; c < 4; c++) {
            int o = o0 + tx * 4 + c;
            if (o < 259) U[(size_t)i * 260 + o] = acc[r][c];
        }
    }
}

// ---------------- K7: final expmap0 + hyp_proj epilogue ----------------
__global__ void k_final_epilogue(const float* __restrict__ U, float* __restrict__ out) {
    __shared__ float part[4];
    int i = blockIdx.x;
    int t = threadIdx.x;
    float a = U[(size_t)i * 260 + t];
    float b = (t < 3) ? U[(size_t)i * 260 + 256 + t] : 0.f;
    float ss = wave_reduce_sum(a * a + b * b);
    if ((t & 63) == 0) part[t >> 6] = ss;
    __syncthreads();
    ss = part[0] + part[1] + part[2] + part[3];
    float nv = fmaxf(sqrtf(ss), MINF);
    float sh = sinhf(nv);
    float scale = sh / nv;
    out[(size_t)i * 260 + 1 + t] = scale * a;
    if (t < 3) out[(size_t)i * 260 + 257 + t] = scale * b;
    if (t == 0) out[(size_t)i * 260] = sqrtf(1.0f + sh * sh);
}

extern "C" void kernel_launch(void* const* d_in, const int* in_sizes, int n_in,
                              void* d_out, int out_size, void* d_ws, size_t ws_size,
                              hipStream_t stream) {
    const float* x = (const float*)d_in[0];
    const float* adj = (const float*)d_in[1];
    const float* W_att = (const float*)d_in[2];
    const float* W_data = (const float*)d_in[3];
    const float* W_out = (const float*)d_in[4];
    const float* W_lin = (const float*)d_in[5];
    float* out = (float*)d_out;

    char* ws = (char*)d_ws;
    size_t off = 0;
    auto alloc = [&](size_t bytes) {
        void* ptr = ws + off;
        off += (bytes + 255) & ~(size_t)255;
        return ptr;
    };
    int* cnt = (int*)alloc((size_t)N * 4);
    int* idx = (int*)alloc((size_t)N * CAP * 4);
    float* lmv = (float*)alloc((size_t)N * 64 * 4);
    float* attv = (float*)alloc((size_t)H * N * 64 * 4); // reused as lmF later
    float2* a0l = (float2*)alloc((size_t)H * N * 8);
    float* pvb = (float*)alloc((size_t)H * N * 64 * 4);  // reused as p later
    float* lm2 = (float*)alloc((size_t)H * N * 64 * 4);
    float* U = (float*)alloc((size_t)N * 260 * 4);
    float* Bp = (float*)alloc((size_t)8 * 4096 * 4);
    float* Bo = (float*)alloc((size_t)4 * 4096 * 4);
    float* lmF = attv;   // alias: attv dead after k_attn
    float* p = pvb;      // alias: pv dead after k_attn

    k_prep<<<1752, 256, 0, stream>>>(x, lmv, W_att, W_data, W_out, Bp, Bo, cnt);
    k_csr_gemm<<<4864, 256, 0, stream>>>(adj, cnt, idx, lmv, Bp, attv, a0l, pvb);
    k_attn<<<dim3(N / 4, H), 256, 0, stream>>>(cnt, idx, attv, a0l, pvb, lm2);
    k_gemm_out<<<dim3(N / 64, H), 256, 0, stream>>>(lm2, Bo, p);
    k_final_logmap<<<N, 256, 0, stream>>>(p, lmF);
    k_final_gemm<<<dim3(N / 64, 5), 256, 0, stream>>>(lmF, W_lin, U);
    k_final_epilogue<<<N, 256, 0, stream>>>(U, out);
}